// Round 1
// baseline (836.487 us; speedup 1.0000x reference)
//
#include <hip/hip_runtime.h>
#include <math.h>

#define N_NODES 50000
#define N_EDGES 800000
#define NRAD 20

__global__ void zero_counts_kernel(int* __restrict__ counts) {
    int i = blockIdx.x * blockDim.x + threadIdx.x;
    if (i < N_NODES) counts[i] = 0;
}

// One wave per node. lane l owns hidden channel l and output channels {l, 64+l, 128+l}.
__global__ __launch_bounds__(256) void node_mlp_kernel(
    const float* __restrict__ ns, const float* __restrict__ W1, const float* __restrict__ b1,
    const float* __restrict__ W2, const float* __restrict__ b2, float* __restrict__ so) {
    __shared__ float w1s[64 * 64];
    __shared__ float w2s[64 * 192];
    int t = threadIdx.x;
    for (int i = t; i < 64 * 64; i += 256) w1s[i] = W1[i];
    for (int i = t; i < 64 * 192; i += 256) w2s[i] = W2[i];
    __syncthreads();
    int l = t & 63;
    int wv = (blockIdx.x * 256 + t) >> 6;
    int nw = gridDim.x * 4;
    float b1l = b1[l];
    float b2l0 = b2[l], b2l1 = b2[64 + l], b2l2 = b2[128 + l];
    for (int n = wv; n < N_NODES; n += nw) {
        float xl = ns[(size_t)n * 64 + l];
        float h = b1l;
#pragma unroll
        for (int k = 0; k < 64; k++) h += __shfl(xl, k) * w1s[k * 64 + l];
        // silu
        h = h / (1.0f + __expf(-h));
        float o0 = b2l0, o1 = b2l1, o2 = b2l2;
#pragma unroll
        for (int k = 0; k < 64; k++) {
            float hk = __shfl(h, k);
            o0 += hk * w2s[k * 192 + l];
            o1 += hk * w2s[k * 192 + 64 + l];
            o2 += hk * w2s[k * 192 + 128 + l];
        }
        size_t base = (size_t)n * 192;
        so[base + l] = o0;
        so[base + 64 + l] = o1;
        so[base + 128 + l] = o2;
    }
}

__global__ void hist_kernel(const int* __restrict__ edge, int* __restrict__ counts) {
    int e = blockIdx.x * blockDim.x + threadIdx.x;
    if (e < N_EDGES) atomicAdd(&counts[edge[2 * e]], 1);
}

__global__ __launch_bounds__(1024) void scan_kernel(const int* __restrict__ counts,
                                                    int* __restrict__ offs,
                                                    int* __restrict__ cursors) {
    __shared__ int sums[1024];
    int t = threadIdx.x;
    const int chunk = (N_NODES + 1023) / 1024;  // 49
    int begin = t * chunk;
    int end = min(begin + chunk, N_NODES);
    int s = 0;
    for (int i = begin; i < end; i++) s += counts[i];
    sums[t] = s;
    __syncthreads();
    for (int off = 1; off < 1024; off <<= 1) {
        int v = (t >= off) ? sums[t - off] : 0;
        __syncthreads();
        sums[t] += v;
        __syncthreads();
    }
    int base = (t == 0) ? 0 : sums[t - 1];
    for (int i = begin; i < end; i++) {
        offs[i] = base;
        cursors[i] = base;
        base += counts[i];
    }
    if (t == 0) offs[N_NODES] = sums[1023];
}

__global__ void bucket_kernel(const int* __restrict__ edge, int* __restrict__ cursors,
                              int* __restrict__ csr) {
    int e = blockIdx.x * blockDim.x + threadIdx.x;
    if (e < N_EDGES) {
        int pos = atomicAdd(&cursors[edge[2 * e]], 1);
        csr[pos] = e;
    }
}

// One wave per destination node; accumulate its incoming messages in registers.
__global__ __launch_bounds__(256) void gather_kernel(
    const float* __restrict__ ns, const float* __restrict__ nv,
    const int* __restrict__ edge, const float* __restrict__ ediff,
    const float* __restrict__ edist, const float* __restrict__ Wf,
    const float* __restrict__ bfv, const float* __restrict__ so,
    const int* __restrict__ offs, const int* __restrict__ csr,
    float* __restrict__ out0, float* __restrict__ out1) {
    int t = threadIdx.x;
    int l = t & 63;
    int n = (blockIdx.x * 256 + t) >> 6;

    float wf0[NRAD], wf1[NRAD], wf2[NRAD];
#pragma unroll
    for (int k = 0; k < NRAD; k++) {
        wf0[k] = Wf[k * 192 + l];
        wf1[k] = Wf[k * 192 + 64 + l];
        wf2[k] = Wf[k * 192 + 128 + l];
    }
    float bf0 = bfv[l], bf1 = bfv[64 + l], bf2 = bfv[128 + l];
    if (n >= N_NODES) return;

    int start = offs[n], end = offs[n + 1];
    float acc_s = 0.0f, a0 = 0.0f, a1 = 0.0f, a2 = 0.0f;

    for (int i = start; i < end; i++) {
        int e = csr[i];
        int src = edge[2 * e + 1];
        float dist = edist[e];
        float d0 = ediff[3 * e], d1 = ediff[3 * e + 1], d2 = ediff[3 * e + 2];
        float inv = __builtin_amdgcn_rcpf(dist);
        float x = dist * (3.14159265358979323846f / 5.0f);
        float s1 = __sinf(x);
        float c1 = __cosf(x);
        // rbf_k = sin(k*x)/dist; recurrence sin((k+1)x) = 2cos(x)sin(kx) - sin((k-1)x)
        float t2 = 2.0f * c1;
        float sn = s1, sp = 0.0f;
        float f0 = 0.0f, f1 = 0.0f, f2 = 0.0f;
#pragma unroll
        for (int k = 0; k < NRAD; k++) {
            f0 += sn * wf0[k];
            f1 += sn * wf1[k];
            f2 += sn * wf2[k];
            float nx = t2 * sn - sp;
            sp = sn;
            sn = nx;
        }
        float cut = (dist < 5.0f) ? 0.5f * (c1 + 1.0f) : 0.0f;
        f0 = (f0 * inv + bf0) * cut;
        f1 = (f1 * inv + bf1) * cut;
        f2 = (f2 * inv + bf2) * cut;

        const float* sr = so + (size_t)src * 192;
        float g0 = f0 * sr[l];         // gate_state_vector
        float g1 = f1 * sr[64 + l];    // gate_edge_vector
        float ms = f2 * sr[128 + l];   // message_scalar
        const float* vr = nv + (size_t)src * 192;
        float u0 = d0 * inv, u1 = d1 * inv, u2 = d2 * inv;
        acc_s += ms;
        a0 += vr[l] * g0 + g1 * u0;
        a1 += vr[64 + l] * g0 + g1 * u1;
        a2 += vr[128 + l] * g0 + g1 * u2;
    }

    size_t b64 = (size_t)n * 64, b192 = (size_t)n * 192;
    out0[b64 + l] = ns[b64 + l] + acc_s;
    out1[b192 + l] = nv[b192 + l] + a0;
    out1[b192 + 64 + l] = nv[b192 + 64 + l] + a1;
    out1[b192 + 128 + l] = nv[b192 + 128 + l] + a2;
}

extern "C" void kernel_launch(void* const* d_in, const int* in_sizes, int n_in,
                              void* d_out, int out_size, void* d_ws, size_t ws_size,
                              hipStream_t stream) {
    const float* ns    = (const float*)d_in[0];
    const float* nv    = (const float*)d_in[1];
    const int*   edge  = (const int*)d_in[2];
    const float* ediff = (const float*)d_in[3];
    const float* edist = (const float*)d_in[4];
    const float* W1    = (const float*)d_in[5];
    const float* b1    = (const float*)d_in[6];
    const float* W2    = (const float*)d_in[7];
    const float* b2    = (const float*)d_in[8];
    const float* Wf    = (const float*)d_in[9];
    const float* bfv   = (const float*)d_in[10];

    float* out0 = (float*)d_out;                       // (N,64)
    float* out1 = out0 + (size_t)N_NODES * 64;         // (N,3,64)

    // workspace layout
    float* so    = (float*)d_ws;                       // (N,192) scalar_out
    int* counts  = (int*)(so + (size_t)N_NODES * 192);
    int* offs    = counts + N_NODES;                   // N+1
    int* cursors = offs + (N_NODES + 1);
    int* csr     = cursors + N_NODES;                  // E

    zero_counts_kernel<<<(N_NODES + 255) / 256, 256, 0, stream>>>(counts);
    node_mlp_kernel<<<512, 256, 0, stream>>>(ns, W1, b1, W2, b2, so);
    hist_kernel<<<(N_EDGES + 255) / 256, 256, 0, stream>>>(edge, counts);
    scan_kernel<<<1, 1024, 0, stream>>>(counts, offs, cursors);
    bucket_kernel<<<(N_EDGES + 255) / 256, 256, 0, stream>>>(edge, cursors, csr);
    gather_kernel<<<N_NODES / 4, 256, 0, stream>>>(ns, nv, edge, ediff, edist, Wf, bfv,
                                                   so, offs, csr, out0, out1);
}

// Round 2
// 543.566 us; speedup vs baseline: 1.5389x; 1.5389x over previous
//
#include <hip/hip_runtime.h>
#include <math.h>

#define N_NODES 50000
#define N_EDGES 800000
#define NRAD 20
#define NBLK 196   // ceil(50000/256)

__global__ void zero_counts_kernel(int* __restrict__ counts) {
    int i = blockIdx.x * blockDim.x + threadIdx.x;
    if (i < N_NODES) counts[i] = 0;
}

// Thread-per-node MLP. Weights are lane-uniform -> scalar pipe (s_load).
// Activations staged transposed in LDS (pad 133 -> conflict-free column reads).
__global__ __launch_bounds__(128) void node_mlp_kernel(
    const float* __restrict__ ns, const float* __restrict__ W1, const float* __restrict__ b1,
    const float* __restrict__ W2, const float* __restrict__ b2, float* __restrict__ so) {
    __shared__ float XT[64 * 133];
    __shared__ float HT[64 * 133];
    int t = threadIdx.x;
    int base = blockIdx.x * 128;
    int nb = min(128, N_NODES - base);

    // stage X tile transposed: XT[k][node_local]
    int total4 = nb * 16;
    const float4* xsrc = (const float4*)(ns + (size_t)base * 64);
    for (int q = t; q < total4; q += 128) {
        float4 v = xsrc[q];
        int node = q >> 4;
        int k = (q & 15) * 4;
        XT[(k + 0) * 133 + node] = v.x;
        XT[(k + 1) * 133 + node] = v.y;
        XT[(k + 2) * 133 + node] = v.z;
        XT[(k + 3) * 133 + node] = v.w;
    }
    __syncthreads();

    bool act = t < nb;
    float h[64];
#pragma unroll
    for (int c = 0; c < 64; c++) h[c] = b1[c];
    if (act) {
        for (int k = 0; k < 64; k++) {
            float xk = XT[k * 133 + t];
            const float* wr = W1 + k * 64;   // lane-uniform -> s_load
#pragma unroll
            for (int c = 0; c < 64; c++) h[c] = fmaf(xk, wr[c], h[c]);
        }
#pragma unroll
        for (int c = 0; c < 64; c++) {
            float v = h[c];
            v = v / (1.0f + __expf(-v));     // silu
            HT[c * 133 + t] = v;
        }
    }
    __syncthreads();

    if (act) {
        size_t ob = (size_t)(base + t) * 192;
        for (int ch = 0; ch < 3; ch++) {
            float o[64];
#pragma unroll
            for (int c = 0; c < 64; c++) o[c] = b2[ch * 64 + c];
            for (int k = 0; k < 64; k++) {
                float hk = HT[k * 133 + t];
                const float* wr = W2 + k * 192 + ch * 64;  // lane-uniform -> s_load
#pragma unroll
                for (int c = 0; c < 64; c++) o[c] = fmaf(hk, wr[c], o[c]);
            }
#pragma unroll
            for (int c = 0; c < 64; c++) so[ob + ch * 64 + c] = o[c];
        }
    }
}

__global__ void hist_kernel(const int* __restrict__ edge, int* __restrict__ counts) {
    int e = blockIdx.x * blockDim.x + threadIdx.x;
    if (e < N_EDGES) atomicAdd(&counts[edge[2 * e]], 1);
}

__global__ __launch_bounds__(256) void scan_part1(const int* __restrict__ counts,
                                                  int* __restrict__ bsum) {
    __shared__ int red[256];
    int t = threadIdx.x, i = blockIdx.x * 256 + t;
    red[t] = (i < N_NODES) ? counts[i] : 0;
    __syncthreads();
    for (int s = 128; s > 0; s >>= 1) {
        if (t < s) red[t] += red[t + s];
        __syncthreads();
    }
    if (t == 0) bsum[blockIdx.x] = red[0];
}

__global__ __launch_bounds__(256) void scan_part2(const int* __restrict__ bsum,
                                                  int* __restrict__ boff) {
    __shared__ int s[256];
    int t = threadIdx.x;
    s[t] = (t < NBLK) ? bsum[t] : 0;
    __syncthreads();
    for (int off = 1; off < 256; off <<= 1) {
        int v = (t >= off) ? s[t - off] : 0;
        __syncthreads();
        s[t] += v;
        __syncthreads();
    }
    boff[t] = (t == 0) ? 0 : s[t - 1];
}

__global__ __launch_bounds__(256) void scan_part3(const int* __restrict__ counts,
                                                  const int* __restrict__ boff,
                                                  int* __restrict__ offs,
                                                  int* __restrict__ cursors) {
    __shared__ int s[256];
    int t = threadIdx.x, b = blockIdx.x, i = b * 256 + t;
    int v = (i < N_NODES) ? counts[i] : 0;
    s[t] = v;
    __syncthreads();
    for (int off = 1; off < 256; off <<= 1) {
        int u = (t >= off) ? s[t - off] : 0;
        __syncthreads();
        s[t] += u;
        __syncthreads();
    }
    int excl = s[t] - v + boff[b];
    if (i < N_NODES) {
        offs[i] = excl;
        cursors[i] = excl;
    }
    if (i == N_NODES - 1) offs[N_NODES] = excl + v;
}

__global__ void bucket_kernel(const int* __restrict__ edge, int* __restrict__ cursors,
                              int2* __restrict__ pack) {
    int e = blockIdx.x * blockDim.x + threadIdx.x;
    if (e < N_EDGES) {
        int dst = edge[2 * e];
        int src = edge[2 * e + 1];
        int pos = atomicAdd(&cursors[dst], 1);
        pack[pos] = make_int2(e, src);
    }
}

// One wave per destination node; accumulate its incoming messages in registers.
__global__ __launch_bounds__(256) void gather_kernel(
    const float* __restrict__ ns, const float* __restrict__ nv,
    const float* __restrict__ ediff, const float* __restrict__ edist,
    const float* __restrict__ Wf, const float* __restrict__ bfv,
    const float* __restrict__ so, const int* __restrict__ offs,
    const int2* __restrict__ pack, float* __restrict__ out0, float* __restrict__ out1) {
    int t = threadIdx.x;
    int l = t & 63;
    int n = (blockIdx.x * 256 + t) >> 6;

    float wf0[NRAD], wf1[NRAD], wf2[NRAD];
#pragma unroll
    for (int k = 0; k < NRAD; k++) {
        wf0[k] = Wf[k * 192 + l];
        wf1[k] = Wf[k * 192 + 64 + l];
        wf2[k] = Wf[k * 192 + 128 + l];
    }
    float bf0 = bfv[l], bf1 = bfv[64 + l], bf2 = bfv[128 + l];
    if (n >= N_NODES) return;

    int start = offs[n], end = offs[n + 1];
    float acc_s = 0.0f, a0 = 0.0f, a1 = 0.0f, a2 = 0.0f;

    int2 pk;
    if (start < end) pk = pack[start];
    for (int i = start; i < end; i++) {
        int2 nxt = (i + 1 < end) ? pack[i + 1] : pk;  // prefetch
        int e = pk.x;
        int src = pk.y;
        float dist = edist[e];
        float d0 = ediff[3 * e], d1 = ediff[3 * e + 1], d2 = ediff[3 * e + 2];
        float inv = __builtin_amdgcn_rcpf(dist);
        float x = dist * (3.14159265358979323846f / 5.0f);
        float s1 = __sinf(x);
        float c1 = __cosf(x);
        float t2 = 2.0f * c1;
        float sn = s1, sp = 0.0f;
        float f0 = 0.0f, f1 = 0.0f, f2 = 0.0f;
#pragma unroll
        for (int k = 0; k < NRAD; k++) {
            f0 += sn * wf0[k];
            f1 += sn * wf1[k];
            f2 += sn * wf2[k];
            float nx = t2 * sn - sp;
            sp = sn;
            sn = nx;
        }
        float cut = (dist < 5.0f) ? 0.5f * (c1 + 1.0f) : 0.0f;
        f0 = (f0 * inv + bf0) * cut;
        f1 = (f1 * inv + bf1) * cut;
        f2 = (f2 * inv + bf2) * cut;

        const float* sr = so + (size_t)src * 192;
        float g0 = f0 * sr[l];
        float g1 = f1 * sr[64 + l];
        float ms = f2 * sr[128 + l];
        const float* vr = nv + (size_t)src * 192;
        float u0 = d0 * inv, u1 = d1 * inv, u2 = d2 * inv;
        acc_s += ms;
        a0 += vr[l] * g0 + g1 * u0;
        a1 += vr[64 + l] * g0 + g1 * u1;
        a2 += vr[128 + l] * g0 + g1 * u2;
        pk = nxt;
    }

    size_t b64 = (size_t)n * 64, b192 = (size_t)n * 192;
    out0[b64 + l] = ns[b64 + l] + acc_s;
    out1[b192 + l] = nv[b192 + l] + a0;
    out1[b192 + 64 + l] = nv[b192 + 64 + l] + a1;
    out1[b192 + 128 + l] = nv[b192 + 128 + l] + a2;
}

extern "C" void kernel_launch(void* const* d_in, const int* in_sizes, int n_in,
                              void* d_out, int out_size, void* d_ws, size_t ws_size,
                              hipStream_t stream) {
    const float* ns    = (const float*)d_in[0];
    const float* nv    = (const float*)d_in[1];
    const int*   edge  = (const int*)d_in[2];
    const float* ediff = (const float*)d_in[3];
    const float* edist = (const float*)d_in[4];
    const float* W1    = (const float*)d_in[5];
    const float* b1    = (const float*)d_in[6];
    const float* W2    = (const float*)d_in[7];
    const float* b2    = (const float*)d_in[8];
    const float* Wf    = (const float*)d_in[9];
    const float* bfv   = (const float*)d_in[10];

    float* out0 = (float*)d_out;                       // (N,64)
    float* out1 = out0 + (size_t)N_NODES * 64;         // (N,3,64)

    // workspace layout
    float* so    = (float*)d_ws;                       // (N,192) scalar_out
    int* counts  = (int*)(so + (size_t)N_NODES * 192);
    int* offs    = counts + N_NODES;                   // N+1
    int* cursors = offs + (N_NODES + 1);
    int* bsum    = cursors + N_NODES;                  // NBLK
    int* boff    = bsum + 256;                         // 256
    int2* pack   = (int2*)(boff + 256);                // E int2

    zero_counts_kernel<<<(N_NODES + 255) / 256, 256, 0, stream>>>(counts);
    node_mlp_kernel<<<(N_NODES + 127) / 128, 128, 0, stream>>>(ns, W1, b1, W2, b2, so);
    hist_kernel<<<(N_EDGES + 255) / 256, 256, 0, stream>>>(edge, counts);
    scan_part1<<<NBLK, 256, 0, stream>>>(counts, bsum);
    scan_part2<<<1, 256, 0, stream>>>(bsum, boff);
    scan_part3<<<NBLK, 256, 0, stream>>>(counts, boff, offs, cursors);
    bucket_kernel<<<(N_EDGES + 255) / 256, 256, 0, stream>>>(edge, cursors, pack);
    gather_kernel<<<N_NODES / 4, 256, 0, stream>>>(ns, nv, ediff, edist, Wf, bfv,
                                                   so, offs, pack, out0, out1);
}